// Round 12
// baseline (86.799 us; speedup 1.0000x reference)
//
#include <hip/hip_runtime.h>
#include <hip/hip_bf16.h>
#include <stdint.h>

typedef float  f32x4   __attribute__((ext_vector_type(4)));
typedef float  f32x16  __attribute__((ext_vector_type(16)));
typedef __bf16 bf16x8  __attribute__((ext_vector_type(8)));
typedef __bf16 bf16x4  __attribute__((ext_vector_type(4)));

static constexpr int NB = 8, NS = 1024, NE = 1024, NH = 16;

#define MFMA16(a, b, c) __builtin_amdgcn_mfma_f32_16x16x32_bf16((a), (b), (c), 0, 0, 0)
#define MFMA32(a, b, c) __builtin_amdgcn_mfma_f32_32x32x16_bf16((a), (b), (c), 0, 0, 0)

__device__ __forceinline__ void gload_lds16(const void* g, void* l) {
    __builtin_amdgcn_global_load_lds(
        (const __attribute__((address_space(1))) void*)g,
        (__attribute__((address_space(3))) void*)l, 16, 0, 0);
}

__device__ __forceinline__ uint32_t cvt_pk_bf16(float lo, float hi) {
    uint32_t r;
    asm("v_cvt_pk_bf16_f32 %0, %1, %2" : "=v"(r) : "v"(lo), "v"(hi));
    return r;
}
__device__ __forceinline__ void pl32swap(uint32_t& a, uint32_t& b) {
    asm volatile("v_permlane32_swap_b32 %0, %1" : "+v"(a), "+v"(b));
}
__device__ __forceinline__ float exp2_raw(float x) {
    float r;
    asm("v_exp_f32 %0, %1" : "=v"(r) : "v"(x));
    return r;
}

// ---------------------------------------------------------------------------
// Kernel 1: proj = cos(x + theta) dual layout, PLUS fused W->bf16 convert.
// ---------------------------------------------------------------------------
__global__ __launch_bounds__(256) void k_proj(const float* __restrict__ x,
                                              const float* __restrict__ theta,
                                              __bf16* __restrict__ proj,
                                              __bf16* __restrict__ projT,
                                              const float* __restrict__ W,
                                              __bf16* __restrict__ Wb) {
    __shared__ float sm[64][65];
    const int bid = blockIdx.x;
    const int t   = threadIdx.x;

    if (bid >= 2048) {  // fused cvtW: 1024 blocks
        const int i = ((bid - 2048) * 256 + t) * 4;
        float4 v = *(const float4*)(W + i);
        bf16x4 o = {(__bf16)v.x, (__bf16)v.y, (__bf16)v.z, (__bf16)v.w};
        *(bf16x4*)(Wb + i) = o;
        return;
    }

    const int bh   = bid >> 4;
    const int st0  = (bid & 15) << 6;
    const int b    = bh >> 4, h = bh & 15;
    const int srow = t >> 2;
    const int j4   = t & 3;

    const float* xrow = x + ((size_t)(b * NS + st0 + srow)) * NE + h * 64;
    __bf16* prow = proj + ((size_t)bh * NS + st0 + srow) * 64;

#pragma unroll
    for (int k = 0; k < 4; ++k) {
        const int d = k * 16 + j4 * 4;
        float4 xv = *(const float4*)(xrow + d);
        float4 tv = *(const float4*)(theta + d);
        float c0 = __cosf(xv.x + tv.x);
        float c1 = __cosf(xv.y + tv.y);
        float c2 = __cosf(xv.z + tv.z);
        float c3 = __cosf(xv.w + tv.w);
        bf16x4 pv = {(__bf16)c0, (__bf16)c1, (__bf16)c2, (__bf16)c3};
        *(bf16x4*)(prow + d) = pv;
        sm[d + 0][srow] = c0;
        sm[d + 1][srow] = c1;
        sm[d + 2][srow] = c2;
        sm[d + 3][srow] = c3;
    }
    __syncthreads();

    const int drow = t >> 2;
    bf16x8 o0, o1;
#pragma unroll
    for (int i = 0; i < 8; ++i) {
        o0[i] = (__bf16)sm[drow][j4 * 16 + i];
        o1[i] = (__bf16)sm[drow][j4 * 16 + 8 + i];
    }
    __bf16* dst = projT + ((size_t)bh * 64 + drow) * NS + st0 + j4 * 16;
    *(bf16x8*)dst = o0;
    *(bf16x8*)(dst + 8) = o1;
}

// ---------------------------------------------------------------------------
// Kernel 3: flash attention — R9 VERBATIM (proven 47.4 us):
//   grid 512, 4 waves x 64 q-rows, KVBLK=64, dbuf LDS, plain
//   STAGE-before-compute loop, XCD-grouped decode, post-MFMA csc scaling.
// ---------------------------------------------------------------------------
__global__ __launch_bounds__(256, 2) void k_attn(const __bf16* __restrict__ proj,
                                                 const __bf16* __restrict__ projT,
                                                 __bf16* __restrict__ attn_out) {
    __shared__ __align__(16) char smem[32768];
    __bf16* const smK0 = (__bf16*)(smem);
    __bf16* const smV0 = (__bf16*)(smem + 8192);
    __bf16* const smK1 = (__bf16*)(smem + 16384);
    __bf16* const smV1 = (__bf16*)(smem + 24576);

    const int bid  = blockIdx.x;        // 0..511
    const int bh   = (bid & 7) + 8 * ((bid >> 3) & 15);  // XCD-grouped decode
    const int qblk = bid >> 7;          // 0..3
    const int t    = threadIdx.x;
    const int w    = t >> 6;
    const int lane = t & 63;
    const int hi   = lane >> 5;
    const int l5   = lane & 31;
    const int l7   = l5 & 7;
    const int qw   = qblk * 256 + w * 64;
    const int b    = bh >> 4, h = bh & 15;

    const __bf16* P  = proj  + (size_t)bh * NS * 64;
    const __bf16* PT = projT + (size_t)bh * 64 * NS;

    const float csc = 0.18033688f;   // (1/sqrt(64)) * log2(e)

    bf16x8 bq[2][4];
#pragma unroll
    for (int q01 = 0; q01 < 2; ++q01)
#pragma unroll
        for (int d = 0; d < 4; ++d)
            bq[q01][d] = *(const bf16x8*)(P + (size_t)(qw + q01 * 32 + l5) * 64 + d * 16 + hi * 8);

    int roff[4];
#pragma unroll
    for (int d = 0; d < 4; ++d) roff[d] = l5 * 64 + ((d * 2 + hi) ^ l7) * 8;

    const int srow  = t >> 3;
    const int sjsrc = (t & 7) ^ (srow & 7);
    char* const dK0 = (char*)smK0 + t * 16;
    char* const dV0 = (char*)smV0 + t * 16;
    char* const dK1 = (char*)smK1 + t * 16;
    char* const dV1 = (char*)smV1 + t * 16;

#define STAGE(kvoff, dk, dv)                                                           \
    do {                                                                               \
        gload_lds16(P  + (size_t)((kvoff) + srow)      * 64 + sjsrc * 8, (dk));        \
        gload_lds16(P  + (size_t)((kvoff) + 32 + srow) * 64 + sjsrc * 8, (dk) + 4096); \
        gload_lds16(PT + (size_t)srow        * NS + (kvoff) + sjsrc * 8, (dv));        \
        gload_lds16(PT + (size_t)(32 + srow) * NS + (kvoff) + sjsrc * 8, (dv) + 4096); \
    } while (0)

    f32x16 acc0[2], acc1[2];
#pragma unroll
    for (int dt = 0; dt < 2; ++dt) {
        acc0[dt] = (f32x16){0.f,0.f,0.f,0.f,0.f,0.f,0.f,0.f,0.f,0.f,0.f,0.f,0.f,0.f,0.f,0.f};
        acc1[dt] = (f32x16){0.f,0.f,0.f,0.f,0.f,0.f,0.f,0.f,0.f,0.f,0.f,0.f,0.f,0.f,0.f,0.f};
    }
    float rs0 = 0.f, rs1 = 0.f;

    auto computeTile = [&](const __bf16* kB, const __bf16* vB) {
#pragma unroll
        for (int kt = 0; kt < 2; ++kt) {
            bf16x8 ak[4];
#pragma unroll
            for (int d = 0; d < 4; ++d)
                ak[d] = *(const bf16x8*)(kB + roff[d] + kt * 2048);

            f32x16 st0 = (f32x16){0.f,0.f,0.f,0.f,0.f,0.f,0.f,0.f,0.f,0.f,0.f,0.f,0.f,0.f,0.f,0.f};
            f32x16 st1 = (f32x16){0.f,0.f,0.f,0.f,0.f,0.f,0.f,0.f,0.f,0.f,0.f,0.f,0.f,0.f,0.f,0.f};
            __builtin_amdgcn_s_setprio(1);
#pragma unroll
            for (int d = 0; d < 4; ++d) {
                st0 = MFMA32(ak[d], bq[0][d], st0);
                st1 = MFMA32(ak[d], bq[1][d], st1);
            }
            __builtin_amdgcn_s_setprio(0);

            uint32_t c0[8], c1[8];
            {
                float p[16];
#pragma unroll
                for (int r = 0; r < 16; ++r) p[r] = exp2_raw(st0[r] * csc);
                rs0 += (((p[0] + p[1]) + (p[2] + p[3])) + ((p[4] + p[5]) + (p[6] + p[7]))) +
                       (((p[8] + p[9]) + (p[10] + p[11])) + ((p[12] + p[13]) + (p[14] + p[15])));
#pragma unroll
                for (int j = 0; j < 8; ++j) c0[j] = cvt_pk_bf16(p[2 * j], p[2 * j + 1]);
            }
            {
                float p[16];
#pragma unroll
                for (int r = 0; r < 16; ++r) p[r] = exp2_raw(st1[r] * csc);
                rs1 += (((p[0] + p[1]) + (p[2] + p[3])) + ((p[4] + p[5]) + (p[6] + p[7]))) +
                       (((p[8] + p[9]) + (p[10] + p[11])) + ((p[12] + p[13]) + (p[14] + p[15])));
#pragma unroll
                for (int j = 0; j < 8; ++j) c1[j] = cvt_pk_bf16(p[2 * j], p[2 * j + 1]);
            }
            pl32swap(c0[0], c0[2]); pl32swap(c0[1], c0[3]);
            pl32swap(c0[4], c0[6]); pl32swap(c0[5], c0[7]);
            pl32swap(c1[0], c1[2]); pl32swap(c1[1], c1[3]);
            pl32swap(c1[4], c1[6]); pl32swap(c1[5], c1[7]);

#pragma unroll
            for (int half = 0; half < 2; ++half) {
                const int ks = kt * 2 + half;
                union U4 { uint32_t u[4]; bf16x8 v; };
                U4 f0, f1;
#pragma unroll
                for (int j = 0; j < 4; ++j) {
                    f0.u[j] = c0[half * 4 + j];
                    f1.u[j] = c1[half * 4 + j];
                }
                __builtin_amdgcn_s_setprio(1);
#pragma unroll
                for (int dt = 0; dt < 2; ++dt) {
                    bf16x8 av = *(const bf16x8*)(vB + roff[ks] + dt * 2048);
                    acc0[dt] = MFMA32(av, f0.v, acc0[dt]);
                    acc1[dt] = MFMA32(av, f1.v, acc1[dt]);
                }
                __builtin_amdgcn_s_setprio(0);
            }
        }
    };

    STAGE(0, dK0, dV0);
    __syncthreads();

#pragma unroll 1
    for (int it2 = 0; it2 < 8; ++it2) {
        STAGE((2 * it2 + 1) * 64, dK1, dV1);
        computeTile(smK0, smV0);
        __syncthreads();
        if (it2 < 7) STAGE((2 * it2 + 2) * 64, dK0, dV0);
        computeTile(smK1, smV1);
        __syncthreads();
    }
#undef STAGE

    float* const epw = (float*)smem + w * (32 * 33);
    const int orow = lane >> 1;
    const int ohalf = lane & 1;

#pragma unroll
    for (int q01 = 0; q01 < 2; ++q01) {
        float rs = (q01 == 0) ? rs0 : rs1;
        rs += __shfl_xor(rs, 32);
        const float inv = 1.0f / rs;
#pragma unroll
        for (int dt = 0; dt < 2; ++dt) {
            const f32x16 a = (q01 == 0) ? acc0[dt] : acc1[dt];
#pragma unroll
            for (int r = 0; r < 16; ++r)
                epw[l5 * 33 + (r & 3) + 8 * (r >> 2) + 4 * hi] = a[r] * inv;
            bf16x8 o0, o1;
#pragma unroll
            for (int i = 0; i < 8; ++i) {
                o0[i] = (__bf16)(epw[orow * 33 + ohalf * 16 + i]);
                o1[i] = (__bf16)(epw[orow * 33 + ohalf * 16 + 8 + i]);
            }
            __bf16* dst = attn_out +
                ((size_t)b * NS + qblk * 256 + w * 64 + q01 * 32 + orow) * NE +
                h * 64 + dt * 32 + ohalf * 16;
            *(bf16x8*)dst = o0;
            *(bf16x8*)(dst + 8) = o1;
        }
    }
}

// ---------------------------------------------------------------------------
// Kernel 4 (retuned): C[M,N] = A[M,K](bf16) x W^T.
// 64x128 tile, BK=32, dbuf LDS (24 KB) -> grid (8,128)=1024 blocks, 4/CU.
// Swizzle for 64B rows: chunk ^= (row>>1)&3 (2-way max = free).
// 4 waves in 2x2: wave tile 32M x 64N, acc 2x4 f32x4.
// ---------------------------------------------------------------------------
__global__ __launch_bounds__(256, 4) void k_gemm(const __bf16* __restrict__ A,
                                                 const __bf16* __restrict__ Bw,
                                                 float* __restrict__ C) {
    constexpr int K = 1024, N = 1024;
    __shared__ __align__(16) __bf16 As[2][64 * 32];
    __shared__ __align__(16) __bf16 Bs[2][128 * 32];

    const int t = threadIdx.x;
    const int lane = t & 63, w = t >> 6;
    const int g = lane >> 4, c = lane & 15;
    const int wr = w >> 1, wc = w & 1;
    const size_t row0 = (size_t)blockIdx.y * 64;
    const size_t col0 = (size_t)blockIdx.x * 128;

    const __bf16* Ag = A  + row0 * K;
    const __bf16* Bg = Bw + col0 * K;

    // Staging: thread t -> LDS row t>>2, chunk t&3 (linear dest);
    // global source chunk = (t&3) ^ ((row>>1)&3).
    const int srow = t >> 2;                  // 0..63
    const int sj   = (t & 3) ^ ((srow >> 1) & 3);

#define GSTAGE(kb, buf)                                                          \
    do {                                                                         \
        gload_lds16(Ag + (size_t)srow * K + (kb) + sj * 8,                       \
                    (char*)&As[buf][0] + t * 16);                                \
        gload_lds16(Bg + (size_t)srow * K + (kb) + sj * 8,                       \
                    (char*)&Bs[buf][0] + t * 16);                                \
        gload_lds16(Bg + (size_t)(64 + srow) * K + (kb) + sj * 8,                \
                    (char*)&Bs[buf][0] + 4096 + t * 16);                         \
    } while (0)

    f32x4 acc[2][4];
#pragma unroll
    for (int m = 0; m < 2; ++m)
#pragma unroll
        for (int n = 0; n < 4; ++n) acc[m][n] = (f32x4){0.f, 0.f, 0.f, 0.f};

    auto computeBuf = [&](int buf) {
        bf16x8 a[2], bfr[4];
#pragma unroll
        for (int m = 0; m < 2; ++m) {
            const int row = wr * 32 + m * 16 + c;
            a[m] = *(const bf16x8*)(&As[buf][row * 32 + (g ^ ((row >> 1) & 3)) * 8]);
        }
#pragma unroll
        for (int n = 0; n < 4; ++n) {
            const int row = wc * 64 + n * 16 + c;
            bfr[n] = *(const bf16x8*)(&Bs[buf][row * 32 + (g ^ ((row >> 1) & 3)) * 8]);
        }
        __builtin_amdgcn_s_setprio(1);
#pragma unroll
        for (int m = 0; m < 2; ++m)
#pragma unroll
            for (int n = 0; n < 4; ++n) acc[m][n] = MFMA16(a[m], bfr[n], acc[m][n]);
        __builtin_amdgcn_s_setprio(0);
    };

    GSTAGE(0, 0);
    __syncthreads();

#pragma unroll 1
    for (int kt = 0; kt < 16; ++kt) {
        GSTAGE(kt * 64 + 32, 1);
        computeBuf(0);
        __syncthreads();
        if (kt < 15) GSTAGE(kt * 64 + 64, 0);
        computeBuf(1);
        __syncthreads();
    }
#undef GSTAGE

#pragma unroll
    for (int m = 0; m < 2; ++m)
#pragma unroll
        for (int n = 0; n < 4; ++n)
#pragma unroll
            for (int r = 0; r < 4; ++r)
                C[(row0 + wr * 32 + m * 16 + 4 * g + r) * N + col0 + wc * 64 + n * 16 + c] =
                    acc[m][n][r];
}

// ---------------------------------------------------------------------------
extern "C" void kernel_launch(void* const* d_in, const int* in_sizes, int n_in,
                              void* d_out, int out_size, void* d_ws, size_t ws_size,
                              hipStream_t stream) {
    const float* x     = (const float*)d_in[0];
    const float* theta = (const float*)d_in[1];
    const float* W     = (const float*)d_in[2];
    float* out = (float*)d_out;

    char* ws = (char*)d_ws;
    __bf16* proj  = (__bf16*)(ws);
    __bf16* projT = (__bf16*)(ws + 16777216);
    __bf16* Wb    = (__bf16*)(ws + 33554432);
    __bf16* ao    = (__bf16*)(ws + 35651584);

    k_proj<<<NB * NH * (NS / 64) + (NE * NE / 4) / 256, 256, 0, stream>>>(
        x, theta, proj, projT, W, Wb);
    k_attn<<<NB * NH * 4, 256, 0, stream>>>(proj, projT, ao);
    dim3 gg(NE / 128, NB * NS / 64);
    k_gemm<<<gg, 256, 0, stream>>>(ao, Wb, out);
}

// Round 13
// 79.740 us; speedup vs baseline: 1.0885x; 1.0885x over previous
//
#include <hip/hip_runtime.h>
#include <hip/hip_bf16.h>
#include <stdint.h>

typedef float  f32x4   __attribute__((ext_vector_type(4)));
typedef float  f32x16  __attribute__((ext_vector_type(16)));
typedef __bf16 bf16x8  __attribute__((ext_vector_type(8)));
typedef __bf16 bf16x4  __attribute__((ext_vector_type(4)));

static constexpr int NB = 8, NS = 1024, NE = 1024, NH = 16;

#define MFMA16(a, b, c) __builtin_amdgcn_mfma_f32_16x16x32_bf16((a), (b), (c), 0, 0, 0)
#define MFMA32(a, b, c) __builtin_amdgcn_mfma_f32_32x32x16_bf16((a), (b), (c), 0, 0, 0)

__device__ __forceinline__ void gload_lds16(const void* g, void* l) {
    __builtin_amdgcn_global_load_lds(
        (const __attribute__((address_space(1))) void*)g,
        (__attribute__((address_space(3))) void*)l, 16, 0, 0);
}

__device__ __forceinline__ uint32_t cvt_pk_bf16(float lo, float hi) {
    uint32_t r;
    asm("v_cvt_pk_bf16_f32 %0, %1, %2" : "=v"(r) : "v"(lo), "v"(hi));
    return r;
}
__device__ __forceinline__ void pl32swap(uint32_t& a, uint32_t& b) {
    asm volatile("v_permlane32_swap_b32 %0, %1" : "+v"(a), "+v"(b));
}
__device__ __forceinline__ float exp2_raw(float x) {
    float r;
    asm("v_exp_f32 %0, %1" : "=v"(r) : "v"(x));
    return r;
}

// ---------------------------------------------------------------------------
// Kernel 1: proj = cos(x + theta) dual layout, PLUS fused W->bf16 convert.
// ---------------------------------------------------------------------------
__global__ __launch_bounds__(256) void k_proj(const float* __restrict__ x,
                                              const float* __restrict__ theta,
                                              __bf16* __restrict__ proj,
                                              __bf16* __restrict__ projT,
                                              const float* __restrict__ W,
                                              __bf16* __restrict__ Wb) {
    __shared__ float sm[64][65];
    const int bid = blockIdx.x;
    const int t   = threadIdx.x;

    if (bid >= 2048) {  // fused cvtW: 1024 blocks
        const int i = ((bid - 2048) * 256 + t) * 4;
        float4 v = *(const float4*)(W + i);
        bf16x4 o = {(__bf16)v.x, (__bf16)v.y, (__bf16)v.z, (__bf16)v.w};
        *(bf16x4*)(Wb + i) = o;
        return;
    }

    const int bh   = bid >> 4;
    const int st0  = (bid & 15) << 6;
    const int b    = bh >> 4, h = bh & 15;
    const int srow = t >> 2;
    const int j4   = t & 3;

    const float* xrow = x + ((size_t)(b * NS + st0 + srow)) * NE + h * 64;
    __bf16* prow = proj + ((size_t)bh * NS + st0 + srow) * 64;

#pragma unroll
    for (int k = 0; k < 4; ++k) {
        const int d = k * 16 + j4 * 4;
        float4 xv = *(const float4*)(xrow + d);
        float4 tv = *(const float4*)(theta + d);
        float c0 = __cosf(xv.x + tv.x);
        float c1 = __cosf(xv.y + tv.y);
        float c2 = __cosf(xv.z + tv.z);
        float c3 = __cosf(xv.w + tv.w);
        bf16x4 pv = {(__bf16)c0, (__bf16)c1, (__bf16)c2, (__bf16)c3};
        *(bf16x4*)(prow + d) = pv;
        sm[d + 0][srow] = c0;
        sm[d + 1][srow] = c1;
        sm[d + 2][srow] = c2;
        sm[d + 3][srow] = c3;
    }
    __syncthreads();

    const int drow = t >> 2;
    bf16x8 o0, o1;
#pragma unroll
    for (int i = 0; i < 8; ++i) {
        o0[i] = (__bf16)sm[drow][j4 * 16 + i];
        o1[i] = (__bf16)sm[drow][j4 * 16 + 8 + i];
    }
    __bf16* dst = projT + ((size_t)bh * 64 + drow) * NS + st0 + j4 * 16;
    *(bf16x8*)dst = o0;
    *(bf16x8*)(dst + 8) = o1;
}

// ---------------------------------------------------------------------------
// Kernel 3: flash attention — R9 VERBATIM (proven 47.4 us).
// ---------------------------------------------------------------------------
__global__ __launch_bounds__(256, 2) void k_attn(const __bf16* __restrict__ proj,
                                                 const __bf16* __restrict__ projT,
                                                 __bf16* __restrict__ attn_out) {
    __shared__ __align__(16) char smem[32768];
    __bf16* const smK0 = (__bf16*)(smem);
    __bf16* const smV0 = (__bf16*)(smem + 8192);
    __bf16* const smK1 = (__bf16*)(smem + 16384);
    __bf16* const smV1 = (__bf16*)(smem + 24576);

    const int bid  = blockIdx.x;
    const int bh   = (bid & 7) + 8 * ((bid >> 3) & 15);
    const int qblk = bid >> 7;
    const int t    = threadIdx.x;
    const int w    = t >> 6;
    const int lane = t & 63;
    const int hi   = lane >> 5;
    const int l5   = lane & 31;
    const int l7   = l5 & 7;
    const int qw   = qblk * 256 + w * 64;
    const int b    = bh >> 4, h = bh & 15;

    const __bf16* P  = proj  + (size_t)bh * NS * 64;
    const __bf16* PT = projT + (size_t)bh * 64 * NS;

    const float csc = 0.18033688f;

    bf16x8 bq[2][4];
#pragma unroll
    for (int q01 = 0; q01 < 2; ++q01)
#pragma unroll
        for (int d = 0; d < 4; ++d)
            bq[q01][d] = *(const bf16x8*)(P + (size_t)(qw + q01 * 32 + l5) * 64 + d * 16 + hi * 8);

    int roff[4];
#pragma unroll
    for (int d = 0; d < 4; ++d) roff[d] = l5 * 64 + ((d * 2 + hi) ^ l7) * 8;

    const int srow  = t >> 3;
    const int sjsrc = (t & 7) ^ (srow & 7);
    char* const dK0 = (char*)smK0 + t * 16;
    char* const dV0 = (char*)smV0 + t * 16;
    char* const dK1 = (char*)smK1 + t * 16;
    char* const dV1 = (char*)smV1 + t * 16;

#define STAGE(kvoff, dk, dv)                                                           \
    do {                                                                               \
        gload_lds16(P  + (size_t)((kvoff) + srow)      * 64 + sjsrc * 8, (dk));        \
        gload_lds16(P  + (size_t)((kvoff) + 32 + srow) * 64 + sjsrc * 8, (dk) + 4096); \
        gload_lds16(PT + (size_t)srow        * NS + (kvoff) + sjsrc * 8, (dv));        \
        gload_lds16(PT + (size_t)(32 + srow) * NS + (kvoff) + sjsrc * 8, (dv) + 4096); \
    } while (0)

    f32x16 acc0[2], acc1[2];
#pragma unroll
    for (int dt = 0; dt < 2; ++dt) {
        acc0[dt] = (f32x16){0.f,0.f,0.f,0.f,0.f,0.f,0.f,0.f,0.f,0.f,0.f,0.f,0.f,0.f,0.f,0.f};
        acc1[dt] = (f32x16){0.f,0.f,0.f,0.f,0.f,0.f,0.f,0.f,0.f,0.f,0.f,0.f,0.f,0.f,0.f,0.f};
    }
    float rs0 = 0.f, rs1 = 0.f;

    auto computeTile = [&](const __bf16* kB, const __bf16* vB) {
#pragma unroll
        for (int kt = 0; kt < 2; ++kt) {
            bf16x8 ak[4];
#pragma unroll
            for (int d = 0; d < 4; ++d)
                ak[d] = *(const bf16x8*)(kB + roff[d] + kt * 2048);

            f32x16 st0 = (f32x16){0.f,0.f,0.f,0.f,0.f,0.f,0.f,0.f,0.f,0.f,0.f,0.f,0.f,0.f,0.f,0.f};
            f32x16 st1 = (f32x16){0.f,0.f,0.f,0.f,0.f,0.f,0.f,0.f,0.f,0.f,0.f,0.f,0.f,0.f,0.f,0.f};
            __builtin_amdgcn_s_setprio(1);
#pragma unroll
            for (int d = 0; d < 4; ++d) {
                st0 = MFMA32(ak[d], bq[0][d], st0);
                st1 = MFMA32(ak[d], bq[1][d], st1);
            }
            __builtin_amdgcn_s_setprio(0);

            uint32_t c0[8], c1[8];
            {
                float p[16];
#pragma unroll
                for (int r = 0; r < 16; ++r) p[r] = exp2_raw(st0[r] * csc);
                rs0 += (((p[0] + p[1]) + (p[2] + p[3])) + ((p[4] + p[5]) + (p[6] + p[7]))) +
                       (((p[8] + p[9]) + (p[10] + p[11])) + ((p[12] + p[13]) + (p[14] + p[15])));
#pragma unroll
                for (int j = 0; j < 8; ++j) c0[j] = cvt_pk_bf16(p[2 * j], p[2 * j + 1]);
            }
            {
                float p[16];
#pragma unroll
                for (int r = 0; r < 16; ++r) p[r] = exp2_raw(st1[r] * csc);
                rs1 += (((p[0] + p[1]) + (p[2] + p[3])) + ((p[4] + p[5]) + (p[6] + p[7]))) +
                       (((p[8] + p[9]) + (p[10] + p[11])) + ((p[12] + p[13]) + (p[14] + p[15])));
#pragma unroll
                for (int j = 0; j < 8; ++j) c1[j] = cvt_pk_bf16(p[2 * j], p[2 * j + 1]);
            }
            pl32swap(c0[0], c0[2]); pl32swap(c0[1], c0[3]);
            pl32swap(c0[4], c0[6]); pl32swap(c0[5], c0[7]);
            pl32swap(c1[0], c1[2]); pl32swap(c1[1], c1[3]);
            pl32swap(c1[4], c1[6]); pl32swap(c1[5], c1[7]);

#pragma unroll
            for (int half = 0; half < 2; ++half) {
                const int ks = kt * 2 + half;
                union U4 { uint32_t u[4]; bf16x8 v; };
                U4 f0, f1;
#pragma unroll
                for (int j = 0; j < 4; ++j) {
                    f0.u[j] = c0[half * 4 + j];
                    f1.u[j] = c1[half * 4 + j];
                }
                __builtin_amdgcn_s_setprio(1);
#pragma unroll
                for (int dt = 0; dt < 2; ++dt) {
                    bf16x8 av = *(const bf16x8*)(vB + roff[ks] + dt * 2048);
                    acc0[dt] = MFMA32(av, f0.v, acc0[dt]);
                    acc1[dt] = MFMA32(av, f1.v, acc1[dt]);
                }
                __builtin_amdgcn_s_setprio(0);
            }
        }
    };

    STAGE(0, dK0, dV0);
    __syncthreads();

#pragma unroll 1
    for (int it2 = 0; it2 < 8; ++it2) {
        STAGE((2 * it2 + 1) * 64, dK1, dV1);
        computeTile(smK0, smV0);
        __syncthreads();
        if (it2 < 7) STAGE((2 * it2 + 2) * 64, dK0, dV0);
        computeTile(smK1, smV1);
        __syncthreads();
    }
#undef STAGE

    float* const epw = (float*)smem + w * (32 * 33);
    const int orow = lane >> 1;
    const int ohalf = lane & 1;

#pragma unroll
    for (int q01 = 0; q01 < 2; ++q01) {
        float rs = (q01 == 0) ? rs0 : rs1;
        rs += __shfl_xor(rs, 32);
        const float inv = 1.0f / rs;
#pragma unroll
        for (int dt = 0; dt < 2; ++dt) {
            const f32x16 a = (q01 == 0) ? acc0[dt] : acc1[dt];
#pragma unroll
            for (int r = 0; r < 16; ++r)
                epw[l5 * 33 + (r & 3) + 8 * (r >> 2) + 4 * hi] = a[r] * inv;
            bf16x8 o0, o1;
#pragma unroll
            for (int i = 0; i < 8; ++i) {
                o0[i] = (__bf16)(epw[orow * 33 + ohalf * 16 + i]);
                o1[i] = (__bf16)(epw[orow * 33 + ohalf * 16 + 8 + i]);
            }
            __bf16* dst = attn_out +
                ((size_t)b * NS + qblk * 256 + w * 64 + q01 * 32 + orow) * NE +
                h * 64 + dt * 32 + ohalf * 16;
            *(bf16x8*)dst = o0;
            *(bf16x8*)(dst + 8) = o1;
        }
    }
}

// ---------------------------------------------------------------------------
// Kernel 4: split-K GEMM. C[M,N] = A[M,K](bf16) x W^T.
// 128x128 tile, 512 threads = 8 waves: waves 0-3 K[0,512), waves 4-7
// K[512,1024); per-wave dataflow identical to R9 (BK=32 step: 4+4
// ds_read_b128, 16 MFMA). LDS 64 KB (dbuf x khalf x {A,B} 8 KB tiles).
// 2 blocks/CU -> 4 waves/SIMD. Combine: upper waves dump f32 acc to LDS,
// lower waves add and write C.
// ---------------------------------------------------------------------------
__global__ __launch_bounds__(512, 2) void k_gemm(const __bf16* __restrict__ A,
                                                 const __bf16* __restrict__ Bw,
                                                 float* __restrict__ C) {
    constexpr int K = 1024, N = 1024;
    __shared__ __align__(16) char smem[65536];
    // As[buf][kh] @ (buf*2+kh)*8192 ; Bs[buf][kh] @ 32768 + (buf*2+kh)*8192

    const int t = threadIdx.x;           // 0..511
    const int lane = t & 63, w = t >> 6; // 8 waves
    const int kh = w >> 2, q = w & 3;
    const int wr = q >> 1, wc = q & 1;
    const int g = lane >> 4, c = lane & 15;
    const size_t row0 = (size_t)blockIdx.x * 128;
    const size_t col0 = (size_t)blockIdx.y * 128;

    // Staging group (256 threads) handles k-half sh.
    const int ts   = t & 255;
    const int sh   = t >> 8;
    const int srow = ts >> 2;                     // 0..63
    const int sj   = (ts & 3) ^ ((srow >> 1) & 3);

    const __bf16* Ag = A  + row0 * K + sh * 512;
    const __bf16* Bg = Bw + col0 * K + sh * 512;

    char* const aD[2] = {smem + sh * 8192,         smem + 16384 + sh * 8192};
    char* const bD[2] = {smem + 32768 + sh * 8192, smem + 49152 + sh * 8192};
    const char* const aR[2] = {smem + kh * 8192,         smem + 16384 + kh * 8192};
    const char* const bR[2] = {smem + 32768 + kh * 8192, smem + 49152 + kh * 8192};

#define GSTAGE(kt, buf)                                                                   \
    do {                                                                                  \
        gload_lds16(Ag + (size_t)srow * K + (kt) * 32 + sj * 8, aD[buf] + ts * 16);       \
        gload_lds16(Ag + (size_t)(64 + srow) * K + (kt) * 32 + sj * 8,                    \
                    aD[buf] + 4096 + ts * 16);                                            \
        gload_lds16(Bg + (size_t)srow * K + (kt) * 32 + sj * 8, bD[buf] + ts * 16);       \
        gload_lds16(Bg + (size_t)(64 + srow) * K + (kt) * 32 + sj * 8,                    \
                    bD[buf] + 4096 + ts * 16);                                            \
    } while (0)

    // Hoisted swizzled fragment offsets (element units within [128][32] tile).
    int aro[4], bro[4];
#pragma unroll
    for (int m = 0; m < 4; ++m) {
        const int ra = wr * 64 + m * 16 + c;
        aro[m] = ra * 32 + (g ^ ((ra >> 1) & 3)) * 8;
        const int rb = wc * 64 + m * 16 + c;
        bro[m] = rb * 32 + (g ^ ((rb >> 1) & 3)) * 8;
    }

    f32x4 acc[4][4];
#pragma unroll
    for (int m = 0; m < 4; ++m)
#pragma unroll
        for (int n = 0; n < 4; ++n) acc[m][n] = (f32x4){0.f, 0.f, 0.f, 0.f};

    auto computeBuf = [&](int buf) {
        bf16x8 a[4], bb[4];
#pragma unroll
        for (int m = 0; m < 4; ++m)
            a[m] = *(const bf16x8*)((const __bf16*)aR[buf] + aro[m]);
#pragma unroll
        for (int n = 0; n < 4; ++n)
            bb[n] = *(const bf16x8*)((const __bf16*)bR[buf] + bro[n]);
        __builtin_amdgcn_s_setprio(1);
#pragma unroll
        for (int m = 0; m < 4; ++m)
#pragma unroll
            for (int n = 0; n < 4; ++n) acc[m][n] = MFMA16(a[m], bb[n], acc[m][n]);
        __builtin_amdgcn_s_setprio(0);
    };

    GSTAGE(0, 0);
    __syncthreads();

#pragma unroll 1
    for (int kt2 = 0; kt2 < 8; ++kt2) {
        GSTAGE(2 * kt2 + 1, 1);
        computeBuf(0);
        __syncthreads();
        if (kt2 < 7) GSTAGE(2 * kt2 + 2, 0);
        computeBuf(1);
        __syncthreads();
    }
#undef GSTAGE

    // Combine the two K-halves: waves 4-7 dump, waves 0-3 add + write.
    float* const dmp = (float*)smem;     // 4 quadrants x 4096 f32 = 64 KB
    if (kh == 1) {
#pragma unroll
        for (int m = 0; m < 4; ++m)
#pragma unroll
            for (int n = 0; n < 4; ++n)
                *(f32x4*)(dmp + q * 4096 + (m * 4 + n) * 256 + lane * 4) = acc[m][n];
    }
    __syncthreads();
    if (kh == 0) {
#pragma unroll
        for (int m = 0; m < 4; ++m)
#pragma unroll
            for (int n = 0; n < 4; ++n) {
                f32x4 v = *(const f32x4*)(dmp + q * 4096 + (m * 4 + n) * 256 + lane * 4);
                acc[m][n] += v;
            }
#pragma unroll
        for (int m = 0; m < 4; ++m)
#pragma unroll
            for (int n = 0; n < 4; ++n)
#pragma unroll
                for (int r = 0; r < 4; ++r)
                    C[(row0 + wr * 64 + m * 16 + 4 * g + r) * N +
                      col0 + wc * 64 + n * 16 + c] = acc[m][n][r];
    }
}

// ---------------------------------------------------------------------------
extern "C" void kernel_launch(void* const* d_in, const int* in_sizes, int n_in,
                              void* d_out, int out_size, void* d_ws, size_t ws_size,
                              hipStream_t stream) {
    const float* x     = (const float*)d_in[0];
    const float* theta = (const float*)d_in[1];
    const float* W     = (const float*)d_in[2];
    float* out = (float*)d_out;

    char* ws = (char*)d_ws;
    __bf16* proj  = (__bf16*)(ws);
    __bf16* projT = (__bf16*)(ws + 16777216);
    __bf16* Wb    = (__bf16*)(ws + 33554432);
    __bf16* ao    = (__bf16*)(ws + 35651584);

    k_proj<<<NB * NH * (NS / 64) + (NE * NE / 4) / 256, 256, 0, stream>>>(
        x, theta, proj, projT, W, Wb);
    k_attn<<<NB * NH * 4, 256, 0, stream>>>(proj, projT, ao);
    dim3 gg(NB * NS / 128, NE / 128);
    k_gemm<<<gg, 512, 0, stream>>>(ao, Wb, out);
}